// Round 1
// baseline (211.619 us; speedup 1.0000x reference)
//
#include <hip/hip_runtime.h>

#define DEV static __device__ __forceinline__

typedef __attribute__((ext_vector_type(8))) short short8;
typedef __attribute__((ext_vector_type(8))) __bf16 bf16x8;
typedef __attribute__((ext_vector_type(4))) float f32x4;

// N=8 agents, B=8192, OBS=128, ACT=32, D=160, E=128, L=8

DEV short f2bf(float f) {
  unsigned u = __builtin_bit_cast(unsigned, f);
  unsigned r = u + 0x7FFFu + ((u >> 16) & 1u);  // RNE
  return (short)(r >> 16);
}
DEV float bf2f(short h) {
  unsigned u = ((unsigned)(unsigned short)h) << 16;
  return __builtin_bit_cast(float, u);
}
DEV f32x4 mfma16(short8 a, short8 b, f32x4 c) {
  return __builtin_amdgcn_mfma_f32_16x16x32_bf16(
      __builtin_bit_cast(bf16x8, a), __builtin_bit_cast(bf16x8, b), c, 0, 0, 0);
}

// Stage a pre-transposed [128 cols][K] bf16 weight block into padded LDS.
// GPC = K/8 granules per col. LDS_STRIDE in shorts (pad +8 => 2-way banks, free).
template <int GPC, int SRC_STRIDE, int LDS_STRIDE>
DEV void stage_bt(short* lds, const short* src, int tid) {
  constexpr int TOTAL = 128 * GPC;  // multiple of 256 for GPC in {16,20}
  #pragma unroll
  for (int g0 = 0; g0 < TOTAL; g0 += 256) {
    int g = g0 + tid;
    int c = g / GPC, kg = g % GPC;
    *(short8*)(lds + c * LDS_STRIDE + kg * 8) =
        *(const short8*)(src + c * SRC_STRIDE + kg * 8);
  }
}

// ---------------- K0: transpose weights fp32 [K][128] -> bf16 [128][K] -------
__global__ __launch_bounds__(256) void k0_tr(const float* __restrict__ Wg,
                                             const float* __restrict__ Wv,
                                             const float* __restrict__ W1,
                                             short* __restrict__ WgT,
                                             short* __restrict__ WvT,
                                             short* __restrict__ W1T) {
  int g = blockIdx.x * 256 + threadIdx.x;  // 184320 granules total
  const float* src;
  short* dst;
  int c, kg;
  if (g < 20480) {  // Wg: 8 x 128c x 20g, K=160
    int n = g / 2560, rem = g % 2560;
    c = rem / 20; kg = rem % 20;
    src = Wg + n * 20480;
    dst = WgT + n * 20480 + c * 160 + kg * 8;
  } else if (g < 36864) {  // Wv: 8 x 128c x 16g, K=128
    int g2 = g - 20480;
    int n = g2 / 2048, rem = g2 % 2048;
    c = rem / 16; kg = rem % 16;
    src = Wv + n * 16384;
    dst = WvT + n * 16384 + c * 128 + kg * 8;
  } else {  // W1: 8 x 128c x 144g, K=1152
    int g3 = g - 36864;
    int n = g3 / 18432, rem = g3 % 18432;
    c = rem / 144; kg = rem % 144;
    src = W1 + (size_t)n * 147456;
    dst = W1T + (size_t)n * 147456 + c * 1152 + kg * 8;
  }
  short8 o;
  #pragma unroll
  for (int j = 0; j < 8; ++j) o[j] = f2bf(src[(size_t)(kg * 8 + j) * 128 + c]);
  *(short8*)dst = o;
}

// ---------------- K1: e = relu(oa @ Wg + bg) -> bf16 ------------------------
__global__ __launch_bounds__(256) void k1_e(const float* __restrict__ obs,
                                            const float* __restrict__ act,
                                            const short* __restrict__ WgT,
                                            const float* __restrict__ bg,
                                            short* __restrict__ eB) {
  __shared__ __align__(16) short BW[128 * 168];
  const int btile = blockIdx.x, n = blockIdx.y, tid = threadIdx.x;
  stage_bt<20, 160, 168>(BW, WgT + n * 20480, tid);
  __syncthreads();
  const int lane = tid & 63, wave = tid >> 6, lr = lane & 15, kg = lane >> 4;
  const int rowbase = btile * 64 + wave * 16;
  f32x4 acc[8];
  #pragma unroll
  for (int m = 0; m < 8; ++m) acc[m] = f32x4{0.f, 0.f, 0.f, 0.f};
  const float* obsp = obs + (size_t)(n * 8192 + rowbase + lr) * 128;
  const float* actp = act + (size_t)(n * 8192 + rowbase + lr) * 32;
  #pragma unroll
  for (int ks = 0; ks < 5; ++ks) {  // K=160: 4 obs steps + 1 act step
    const float* ap = (ks < 4) ? (obsp + ks * 32 + kg * 8) : (actp + kg * 8);
    float4 p0 = *(const float4*)ap;
    float4 p1 = *(const float4*)(ap + 4);
    short8 a;
    a[0] = f2bf(p0.x); a[1] = f2bf(p0.y); a[2] = f2bf(p0.z); a[3] = f2bf(p0.w);
    a[4] = f2bf(p1.x); a[5] = f2bf(p1.y); a[6] = f2bf(p1.z); a[7] = f2bf(p1.w);
    #pragma unroll
    for (int m = 0; m < 8; ++m) {
      short8 b = *(const short8*)(&BW[(m * 16 + lr) * 168 + ks * 32 + kg * 8]);
      acc[m] = mfma16(a, b, acc[m]);
    }
  }
  #pragma unroll
  for (int m = 0; m < 8; ++m) {
    float bgv = bg[n * 128 + m * 16 + lr];
    #pragma unroll
    for (int r = 0; r < 4; ++r) {
      float x = acc[m][r] + bgv;
      x = x > 0.f ? x : 0.f;
      eB[(size_t)(n * 8192 + rowbase + kg * 4 + r) * 128 + m * 16 + lr] = f2bf(x);
    }
  }
}

// ---------------- K2: S[l] = sum_j leaky(e[j] @ Wv[l] + bv[l]) -> bf16 ------
__global__ __launch_bounds__(256) void k2_S(const short* __restrict__ eB,
                                            const short* __restrict__ WvT,
                                            const float* __restrict__ bv,
                                            short* __restrict__ SB) {
  __shared__ __align__(16) short BW[128 * 136];
  const int btile = blockIdx.x, l = blockIdx.y, tid = threadIdx.x;
  stage_bt<16, 128, 136>(BW, WvT + l * 16384, tid);
  __syncthreads();
  const int lane = tid & 63, wave = tid >> 6, lr = lane & 15, kg = lane >> 4;
  const int rowbase = btile * 64 + wave * 16;
  f32x4 Sacc[8];
  #pragma unroll
  for (int m = 0; m < 8; ++m) Sacc[m] = f32x4{0.f, 0.f, 0.f, 0.f};
  float bvv[8];
  #pragma unroll
  for (int m = 0; m < 8; ++m) bvv[m] = bv[l * 128 + m * 16 + lr];
  for (int j = 0; j < 8; ++j) {
    f32x4 acc[8];
    #pragma unroll
    for (int m = 0; m < 8; ++m) acc[m] = f32x4{0.f, 0.f, 0.f, 0.f};
    const short* ep = eB + (size_t)(j * 8192 + rowbase + lr) * 128;
    #pragma unroll
    for (int ks = 0; ks < 4; ++ks) {
      short8 a = *(const short8*)(ep + ks * 32 + kg * 8);
      #pragma unroll
      for (int m = 0; m < 8; ++m) {
        short8 b = *(const short8*)(&BW[(m * 16 + lr) * 136 + ks * 32 + kg * 8]);
        acc[m] = mfma16(a, b, acc[m]);
      }
    }
    #pragma unroll
    for (int m = 0; m < 8; ++m)
      #pragma unroll
      for (int r = 0; r < 4; ++r) {
        float x = acc[m][r] + bvv[m];
        x = x > 0.f ? x : 0.01f * x;  // leaky_relu slope 0.01
        Sacc[m][r] += x;
      }
  }
  #pragma unroll
  for (int m = 0; m < 8; ++m)
    #pragma unroll
    for (int r = 0; r < 4; ++r)
      SB[(size_t)(l * 8192 + rowbase + kg * 4 + r) * 128 + m * 16 + lr] = f2bf(Sacc[m][r]);
}

// ---------------- K3: fused h = relu(...@W1+b1); out = h.W2 + b2 ------------
__global__ __launch_bounds__(256) void k3_out(const short* __restrict__ eB,
                                              const short* __restrict__ SB,
                                              const short* __restrict__ WvT,
                                              const short* __restrict__ W1T,
                                              const float* __restrict__ bv,
                                              const float* __restrict__ b1,
                                              const float* __restrict__ W2,
                                              const float* __restrict__ b2,
                                              float* __restrict__ out) {
  __shared__ __align__(16) short BW[128 * 136];
  __shared__ __align__(16) short Vbuf[64 * 136];
  const int btile = blockIdx.x, i = blockIdx.y, tid = threadIdx.x;
  const int lane = tid & 63, wave = tid >> 6, lr = lane & 15, kg = lane >> 4;
  const int rowbase = btile * 64 + wave * 16;

  // e A-fragments held in registers across the whole kernel (K=128 -> 4 steps)
  short8 ea[4];
  {
    const short* ep = eB + (size_t)(i * 8192 + rowbase + lr) * 128;
    #pragma unroll
    for (int ks = 0; ks < 4; ++ks) ea[ks] = *(const short8*)(ep + ks * 32 + kg * 8);
  }
  f32x4 hacc[8];
  #pragma unroll
  for (int m = 0; m < 8; ++m) hacc[m] = f32x4{0.f, 0.f, 0.f, 0.f};

  for (int l = 0; l < 8; ++l) {
    __syncthreads();  // previous BW consumers done
    stage_bt<16, 128, 136>(BW, WvT + l * 16384, tid);
    __syncthreads();
    // v = e @ Wv[l]
    f32x4 vacc[8];
    #pragma unroll
    for (int m = 0; m < 8; ++m) vacc[m] = f32x4{0.f, 0.f, 0.f, 0.f};
    #pragma unroll
    for (int ks = 0; ks < 4; ++ks)
      #pragma unroll
      for (int m = 0; m < 8; ++m) {
        short8 b = *(const short8*)(&BW[(m * 16 + lr) * 136 + ks * 32 + kg * 8]);
        vacc[m] = mfma16(ea[ks], b, vacc[m]);
      }
    // bias + leaky_relu, write v to Vbuf in C-layout positions (bf16)
    #pragma unroll
    for (int m = 0; m < 8; ++m) {
      float bb = bv[l * 128 + m * 16 + lr];
      #pragma unroll
      for (int r = 0; r < 4; ++r) {
        float x = vacc[m][r] + bb;
        x = x > 0.f ? x : 0.01f * x;
        Vbuf[(wave * 16 + kg * 4 + r) * 136 + m * 16 + lr] = f2bf(x);
      }
    }
    __syncthreads();  // Vbuf visible; BW free for restage
    stage_bt<16, 1152, 136>(BW, W1T + (size_t)i * 147456 + l * 128, tid);
    __syncthreads();
    // hacc += (S[l] - v) @ W1l[i]
    const short* sp = SB + (size_t)(l * 8192 + rowbase + lr) * 128;
    #pragma unroll
    for (int ks = 0; ks < 4; ++ks) {
      short8 sv = *(const short8*)(sp + ks * 32 + kg * 8);
      short8 vv = *(const short8*)(&Vbuf[(wave * 16 + lr) * 136 + ks * 32 + kg * 8]);
      short8 a;
      #pragma unroll
      for (int jj = 0; jj < 8; ++jj) a[jj] = f2bf(bf2f(sv[jj]) - bf2f(vv[jj]));
      #pragma unroll
      for (int m = 0; m < 8; ++m) {
        short8 b = *(const short8*)(&BW[(m * 16 + lr) * 136 + ks * 32 + kg * 8]);
        hacc[m] = mfma16(a, b, hacc[m]);
      }
    }
  }
  // hacc += e @ W1e[i]  (rows 1024..1151 of W1)
  __syncthreads();
  stage_bt<16, 1152, 136>(BW, W1T + (size_t)i * 147456 + 1024, tid);
  __syncthreads();
  #pragma unroll
  for (int ks = 0; ks < 4; ++ks)
    #pragma unroll
    for (int m = 0; m < 8; ++m) {
      short8 b = *(const short8*)(&BW[(m * 16 + lr) * 136 + ks * 32 + kg * 8]);
      hacc[m] = mfma16(ea[ks], b, hacc[m]);
    }

  // epilogue: h = relu(hacc + b1); out = h . W2 + b2 (reduce over 128 cols)
  float sacc[4] = {0.f, 0.f, 0.f, 0.f};
  #pragma unroll
  for (int m = 0; m < 8; ++m) {
    int col = m * 16 + lr;
    float b1v = b1[i * 128 + col];
    float w2v = W2[i * 128 + col];
    #pragma unroll
    for (int r = 0; r < 4; ++r) {
      float h = hacc[m][r] + b1v;
      h = h > 0.f ? h : 0.f;
      sacc[r] += h * w2v;
    }
  }
  #pragma unroll
  for (int r = 0; r < 4; ++r) {
    float s = sacc[r];
    s += __shfl_xor(s, 1);
    s += __shfl_xor(s, 2);
    s += __shfl_xor(s, 4);
    s += __shfl_xor(s, 8);
    if (lr == 0) out[i * 8192 + rowbase + kg * 4 + r] = s + b2[i];
  }
}

extern "C" void kernel_launch(void* const* d_in, const int* in_sizes, int n_in,
                              void* d_out, int out_size, void* d_ws, size_t ws_size,
                              hipStream_t stream) {
  const float* obs = (const float*)d_in[0];
  const float* act = (const float*)d_in[1];
  const float* Wg  = (const float*)d_in[2];
  const float* bg  = (const float*)d_in[3];
  // d_in[4..7] = Wq,bq,Wk,bk: dead (softmax over singleton axis == 1)
  const float* Wv  = (const float*)d_in[8];
  const float* bv  = (const float*)d_in[9];
  const float* W1  = (const float*)d_in[10];
  const float* b1  = (const float*)d_in[11];
  const float* W2  = (const float*)d_in[12];
  const float* b2  = (const float*)d_in[13];
  float* out = (float*)d_out;

  // workspace layout (bf16 elements): total 36,503,552 bytes
  short* eB  = (short*)d_ws;                    // [8][8192][128]
  short* SB  = eB + (size_t)8 * 8192 * 128;     // [8][8192][128]
  short* WgT = SB + (size_t)8 * 8192 * 128;     // [8][128][160]
  short* WvT = WgT + 8 * 128 * 160;             // [8][128][128]
  short* W1T = WvT + 8 * 128 * 128;             // [8][128][1152]

  k0_tr<<<720, 256, 0, stream>>>(Wg, Wv, W1, WgT, WvT, W1T);
  k1_e<<<dim3(128, 8), 256, 0, stream>>>(obs, act, WgT, bg, eB);
  k2_S<<<dim3(128, 8), 256, 0, stream>>>(eB, WvT, bv, SB);
  k3_out<<<dim3(128, 8), 256, 0, stream>>>(eB, SB, WvT, W1T, bv, b1, W2, b2, out);
}

// Round 2
// 122.899 us; speedup vs baseline: 1.7219x; 1.7219x over previous
//
#include <hip/hip_runtime.h>

#define DEV static __device__ __forceinline__

typedef __attribute__((ext_vector_type(8))) short short8;
typedef __attribute__((ext_vector_type(8))) __bf16 bf16x8;
typedef __attribute__((ext_vector_type(4))) float f32x4;

// N=8 agents, B=8192, OBS=128, ACT=32, D=160, E=128, L=8

DEV short f2bf(float f) {
  unsigned u = __builtin_bit_cast(unsigned, f);
  unsigned r = u + 0x7FFFu + ((u >> 16) & 1u);  // RNE
  return (short)(r >> 16);
}
DEV float bf2f(short h) {
  unsigned u = ((unsigned)(unsigned short)h) << 16;
  return __builtin_bit_cast(float, u);
}
DEV f32x4 mfma16(short8 a, short8 b, f32x4 c) {
  return __builtin_amdgcn_mfma_f32_16x16x32_bf16(
      __builtin_bit_cast(bf16x8, a), __builtin_bit_cast(bf16x8, b), c, 0, 0, 0);
}
DEV void async_copy16(short* lds, const short* g) {
  __builtin_amdgcn_global_load_lds(
      (const __attribute__((address_space(1))) void*)g,
      (__attribute__((address_space(3))) void*)lds, 16, 0, 0);
}

// Stage a pre-transposed [128 cols][K] bf16 weight block into padded LDS.
// GPC = K/8 granules per col. LDS_STRIDE in shorts (pad 8 => stride 17/21
// granules, odd => b128 reads spread uniformly over the 8 bank-slots).
template <int GPC, int SRC_STRIDE, int LDS_STRIDE>
DEV void stage_bt(short* lds, const short* src, int tid) {
  constexpr int TOTAL = 128 * GPC;
  #pragma unroll
  for (int g0 = 0; g0 < TOTAL; g0 += 256) {
    int g = g0 + tid;
    int c = g / GPC, kg = g % GPC;
    *(short8*)(lds + c * LDS_STRIDE + kg * 8) =
        *(const short8*)(src + c * SRC_STRIDE + kg * 8);
  }
}

// ---------------- K0: transpose weights fp32 [K][128] -> bf16 [128][K] -------
__global__ __launch_bounds__(256) void k0_tr(const float* __restrict__ Wg,
                                             const float* __restrict__ Wv,
                                             const float* __restrict__ W1,
                                             short* __restrict__ WgT,
                                             short* __restrict__ WvT,
                                             short* __restrict__ W1T) {
  int g = blockIdx.x * 256 + threadIdx.x;  // 184320 granules total
  const float* src;
  short* dst;
  int c, kg;
  if (g < 20480) {  // Wg: 8 x 128c x 20g, K=160
    int n = g / 2560, rem = g % 2560;
    c = rem / 20; kg = rem % 20;
    src = Wg + n * 20480;
    dst = WgT + n * 20480 + c * 160 + kg * 8;
  } else if (g < 36864) {  // Wv: 8 x 128c x 16g, K=128
    int g2 = g - 20480;
    int n = g2 / 2048, rem = g2 % 2048;
    c = rem / 16; kg = rem % 16;
    src = Wv + n * 16384;
    dst = WvT + n * 16384 + c * 128 + kg * 8;
  } else {  // W1: 8 x 128c x 144g, K=1152
    int g3 = g - 36864;
    int n = g3 / 18432, rem = g3 % 18432;
    c = rem / 144; kg = rem % 144;
    src = W1 + (size_t)n * 147456;
    dst = W1T + (size_t)n * 147456 + c * 1152 + kg * 8;
  }
  short8 o;
  #pragma unroll
  for (int j = 0; j < 8; ++j) o[j] = f2bf(src[(size_t)(kg * 8 + j) * 128 + c]);
  *(short8*)dst = o;
}

// ---------------- K1: e = relu(oa @ Wg + bg) -> bf16 ------------------------
__global__ __launch_bounds__(256) void k1_e(const float* __restrict__ obs,
                                            const float* __restrict__ act,
                                            const short* __restrict__ WgT,
                                            const float* __restrict__ bg,
                                            short* __restrict__ eB) {
  __shared__ __align__(16) short BW[128 * 168];
  const int btile = blockIdx.x, n = blockIdx.y, tid = threadIdx.x;
  stage_bt<20, 160, 168>(BW, WgT + n * 20480, tid);
  __syncthreads();
  const int lane = tid & 63, wave = tid >> 6, lr = lane & 15, kg = lane >> 4;
  const int rowbase = btile * 64 + wave * 16;
  f32x4 acc[8];
  #pragma unroll
  for (int m = 0; m < 8; ++m) acc[m] = f32x4{0.f, 0.f, 0.f, 0.f};
  const float* obsp = obs + (size_t)(n * 8192 + rowbase + lr) * 128;
  const float* actp = act + (size_t)(n * 8192 + rowbase + lr) * 32;
  #pragma unroll
  for (int ks = 0; ks < 5; ++ks) {  // K=160: 4 obs steps + 1 act step
    const float* ap = (ks < 4) ? (obsp + ks * 32 + kg * 8) : (actp + kg * 8);
    float4 p0 = *(const float4*)ap;
    float4 p1 = *(const float4*)(ap + 4);
    short8 a;
    a[0] = f2bf(p0.x); a[1] = f2bf(p0.y); a[2] = f2bf(p0.z); a[3] = f2bf(p0.w);
    a[4] = f2bf(p1.x); a[5] = f2bf(p1.y); a[6] = f2bf(p1.z); a[7] = f2bf(p1.w);
    #pragma unroll
    for (int m = 0; m < 8; ++m) {
      short8 b = *(const short8*)(&BW[(m * 16 + lr) * 168 + ks * 32 + kg * 8]);
      acc[m] = mfma16(a, b, acc[m]);
    }
  }
  #pragma unroll
  for (int m = 0; m < 8; ++m) {
    float bgv = bg[n * 128 + m * 16 + lr];
    #pragma unroll
    for (int r = 0; r < 4; ++r) {
      float x = acc[m][r] + bgv;
      x = x > 0.f ? x : 0.f;
      eB[(size_t)(n * 8192 + rowbase + kg * 4 + r) * 128 + m * 16 + lr] = f2bf(x);
    }
  }
}

// ======================= BIG-WORKSPACE FAST PATH ============================
// K2A: per (btile,l): S = sum_j leaky(e_j@Wv_l+bv_l)  (pass 1, regs only),
// then pass 2 recomputes v_j and writes A[j] = S - v_j into AB[j][row][l*128+c]
__global__ __launch_bounds__(256) void k2_A(const short* __restrict__ eB,
                                            const short* __restrict__ WvT,
                                            const float* __restrict__ bv,
                                            short* __restrict__ AB) {
  __shared__ __align__(16) short BW[128 * 136];
  const int btile = blockIdx.x, l = blockIdx.y, tid = threadIdx.x;
  stage_bt<16, 128, 136>(BW, WvT + l * 16384, tid);
  __syncthreads();
  const int lane = tid & 63, wave = tid >> 6, lr = lane & 15, kg = lane >> 4;
  const int rowbase = btile * 64 + wave * 16;
  float bvv[8];
  #pragma unroll
  for (int m = 0; m < 8; ++m) bvv[m] = bv[l * 128 + m * 16 + lr];
  f32x4 Sacc[8];
  #pragma unroll
  for (int m = 0; m < 8; ++m) Sacc[m] = f32x4{0.f, 0.f, 0.f, 0.f};
  // pass 1: accumulate S
  for (int j = 0; j < 8; ++j) {
    f32x4 acc[8];
    #pragma unroll
    for (int m = 0; m < 8; ++m) acc[m] = f32x4{0.f, 0.f, 0.f, 0.f};
    const short* ep = eB + (size_t)(j * 8192 + rowbase + lr) * 128;
    #pragma unroll
    for (int ks = 0; ks < 4; ++ks) {
      short8 a = *(const short8*)(ep + ks * 32 + kg * 8);
      #pragma unroll
      for (int m = 0; m < 8; ++m) {
        short8 b = *(const short8*)(&BW[(m * 16 + lr) * 136 + ks * 32 + kg * 8]);
        acc[m] = mfma16(a, b, acc[m]);
      }
    }
    #pragma unroll
    for (int m = 0; m < 8; ++m)
      #pragma unroll
      for (int r = 0; r < 4; ++r) {
        float x = acc[m][r] + bvv[m];
        Sacc[m][r] += (x > 0.f ? x : 0.01f * x);
      }
  }
  // pass 2: recompute v_j, write A = S - v_j
  for (int j = 0; j < 8; ++j) {
    f32x4 acc[8];
    #pragma unroll
    for (int m = 0; m < 8; ++m) acc[m] = f32x4{0.f, 0.f, 0.f, 0.f};
    const short* ep = eB + (size_t)(j * 8192 + rowbase + lr) * 128;
    #pragma unroll
    for (int ks = 0; ks < 4; ++ks) {
      short8 a = *(const short8*)(ep + ks * 32 + kg * 8);
      #pragma unroll
      for (int m = 0; m < 8; ++m) {
        short8 b = *(const short8*)(&BW[(m * 16 + lr) * 136 + ks * 32 + kg * 8]);
        acc[m] = mfma16(a, b, acc[m]);
      }
    }
    #pragma unroll
    for (int m = 0; m < 8; ++m)
      #pragma unroll
      for (int r = 0; r < 4; ++r) {
        float x = acc[m][r] + bvv[m];
        float Av = Sacc[m][r] - (x > 0.f ? x : 0.01f * x);
        AB[(size_t)(j * 8192 + rowbase + kg * 4 + r) * 1024 + l * 128 + m * 16 + lr] =
            f2bf(Av);
      }
  }
}

// K3G: per agent i, clean DB GEMM: h = relu([A_i, e_i] @ W1[i] + b1); out=h.W2+b2
// BM=128 rows/block, 9 K-chunks of 128; W1 chunks staged via global_load_lds
// with XOR swizzle (source pre-swizzled, read swizzled -> uniform bank slots).
__global__ __launch_bounds__(256) void k3_gemm(const short* __restrict__ eB,
                                               const short* __restrict__ AB,
                                               const short* __restrict__ W1T,
                                               const float* __restrict__ b1,
                                               const float* __restrict__ W2,
                                               const float* __restrict__ b2,
                                               float* __restrict__ out) {
  __shared__ __align__(16) short BW[2][128 * 128];
  const int btile = blockIdx.x, i = blockIdx.y, tid = threadIdx.x;
  const int lane = tid & 63, wave = tid >> 6, lr = lane & 15, kg = lane >> 4;
  const short* w1 = W1T + (size_t)i * 147456;
  const int lr8 = lane & 7;  // for read swizzle (c&7 with c=m*16+lr)

  // stage chunk c (k rows c*128..c*128+127) into buf; linear LDS [128c][128k],
  // data at (c,gl) placed at physical granule gl^(c&7) via pre-swizzled source.
  #define STAGE(buf, c)                                                        \
    {                                                                          \
      _Pragma("unroll") for (int t = 0; t < 8; ++t) {                          \
        int G = t * 256 + tid;                                                 \
        int cG = G >> 4, gl = G & 15;                                          \
        const short* src = w1 + cG * 1152 + (c) * 128 + ((gl ^ (cG & 7)) << 3);\
        async_copy16((buf) + (t * 256 + wave * 64) * 8, src);                  \
      }                                                                        \
    }

  f32x4 acc[2][8];
  #pragma unroll
  for (int s = 0; s < 2; ++s)
    #pragma unroll
    for (int m = 0; m < 8; ++m) acc[s][m] = f32x4{0.f, 0.f, 0.f, 0.f};

  const short* abase = AB + ((size_t)i * 8192 + btile * 128 + wave * 32 + lr) * 1024;
  const short* ebase = eB + ((size_t)i * 8192 + btile * 128 + wave * 32 + lr) * 128;

  STAGE(BW[0], 0);
  for (int c = 0; c < 9; ++c) {
    __syncthreads();  // stage(c) complete (vmcnt drained); buf[(c+1)&1] free
    if (c < 8) { STAGE(BW[(c + 1) & 1], c + 1); }
    const short* bw = BW[c & 1];
    short8 a[2][4];
    if (c < 8) {
      #pragma unroll
      for (int s = 0; s < 2; ++s)
        #pragma unroll
        for (int ks = 0; ks < 4; ++ks)
          a[s][ks] = *(const short8*)(abase + s * 16384 + c * 128 + ks * 32 + kg * 8);
    } else {
      #pragma unroll
      for (int s = 0; s < 2; ++s)
        #pragma unroll
        for (int ks = 0; ks < 4; ++ks)
          a[s][ks] = *(const short8*)(ebase + s * 2048 + ks * 32 + kg * 8);
    }
    #pragma unroll
    for (int ks = 0; ks < 4; ++ks)
      #pragma unroll
      for (int m = 0; m < 8; ++m) {
        int gl = (ks * 4 + kg) ^ lr8;
        short8 b = *(const short8*)(bw + (m * 16 + lr) * 128 + gl * 8);
        acc[0][m] = mfma16(a[0][ks], b, acc[0][m]);
        acc[1][m] = mfma16(a[1][ks], b, acc[1][m]);
      }
  }
  #undef STAGE

  // epilogue: h = relu(acc + b1); out = h . W2 + b2
  #pragma unroll
  for (int s = 0; s < 2; ++s) {
    float sacc[4] = {0.f, 0.f, 0.f, 0.f};
    #pragma unroll
    for (int m = 0; m < 8; ++m) {
      int col = m * 16 + lr;
      float b1v = b1[i * 128 + col];
      float w2v = W2[i * 128 + col];
      #pragma unroll
      for (int r = 0; r < 4; ++r) {
        float h = acc[s][m][r] + b1v;
        h = h > 0.f ? h : 0.f;
        sacc[r] += h * w2v;
      }
    }
    #pragma unroll
    for (int r = 0; r < 4; ++r) {
      float v = sacc[r];
      v += __shfl_xor(v, 1);
      v += __shfl_xor(v, 2);
      v += __shfl_xor(v, 4);
      v += __shfl_xor(v, 8);
      if (lr == 0)
        out[i * 8192 + btile * 128 + wave * 32 + s * 16 + kg * 4 + r] = v + b2[i];
    }
  }
}

// ======================= SMALL-WORKSPACE FALLBACK ===========================
__global__ __launch_bounds__(256) void k2_S(const short* __restrict__ eB,
                                            const short* __restrict__ WvT,
                                            const float* __restrict__ bv,
                                            short* __restrict__ SB) {
  __shared__ __align__(16) short BW[128 * 136];
  const int btile = blockIdx.x, l = blockIdx.y, tid = threadIdx.x;
  stage_bt<16, 128, 136>(BW, WvT + l * 16384, tid);
  __syncthreads();
  const int lane = tid & 63, wave = tid >> 6, lr = lane & 15, kg = lane >> 4;
  const int rowbase = btile * 64 + wave * 16;
  f32x4 Sacc[8];
  #pragma unroll
  for (int m = 0; m < 8; ++m) Sacc[m] = f32x4{0.f, 0.f, 0.f, 0.f};
  float bvv[8];
  #pragma unroll
  for (int m = 0; m < 8; ++m) bvv[m] = bv[l * 128 + m * 16 + lr];
  for (int j = 0; j < 8; ++j) {
    f32x4 acc[8];
    #pragma unroll
    for (int m = 0; m < 8; ++m) acc[m] = f32x4{0.f, 0.f, 0.f, 0.f};
    const short* ep = eB + (size_t)(j * 8192 + rowbase + lr) * 128;
    #pragma unroll
    for (int ks = 0; ks < 4; ++ks) {
      short8 a = *(const short8*)(ep + ks * 32 + kg * 8);
      #pragma unroll
      for (int m = 0; m < 8; ++m) {
        short8 b = *(const short8*)(&BW[(m * 16 + lr) * 136 + ks * 32 + kg * 8]);
        acc[m] = mfma16(a, b, acc[m]);
      }
    }
    #pragma unroll
    for (int m = 0; m < 8; ++m)
      #pragma unroll
      for (int r = 0; r < 4; ++r) {
        float x = acc[m][r] + bvv[m];
        x = x > 0.f ? x : 0.01f * x;
        Sacc[m][r] += x;
      }
  }
  #pragma unroll
  for (int m = 0; m < 8; ++m)
    #pragma unroll
    for (int r = 0; r < 4; ++r)
      SB[(size_t)(l * 8192 + rowbase + kg * 4 + r) * 128 + m * 16 + lr] = f2bf(Sacc[m][r]);
}

__global__ __launch_bounds__(256) void k3_out(const short* __restrict__ eB,
                                              const short* __restrict__ SB,
                                              const short* __restrict__ WvT,
                                              const short* __restrict__ W1T,
                                              const float* __restrict__ bv,
                                              const float* __restrict__ b1,
                                              const float* __restrict__ W2,
                                              const float* __restrict__ b2,
                                              float* __restrict__ out) {
  __shared__ __align__(16) short BW[128 * 136];
  __shared__ __align__(16) short Vbuf[64 * 136];
  const int btile = blockIdx.x, i = blockIdx.y, tid = threadIdx.x;
  const int lane = tid & 63, wave = tid >> 6, lr = lane & 15, kg = lane >> 4;
  const int rowbase = btile * 64 + wave * 16;
  short8 ea[4];
  {
    const short* ep = eB + (size_t)(i * 8192 + rowbase + lr) * 128;
    #pragma unroll
    for (int ks = 0; ks < 4; ++ks) ea[ks] = *(const short8*)(ep + ks * 32 + kg * 8);
  }
  f32x4 hacc[8];
  #pragma unroll
  for (int m = 0; m < 8; ++m) hacc[m] = f32x4{0.f, 0.f, 0.f, 0.f};
  for (int l = 0; l < 8; ++l) {
    __syncthreads();
    stage_bt<16, 128, 136>(BW, WvT + l * 16384, tid);
    __syncthreads();
    f32x4 vacc[8];
    #pragma unroll
    for (int m = 0; m < 8; ++m) vacc[m] = f32x4{0.f, 0.f, 0.f, 0.f};
    #pragma unroll
    for (int ks = 0; ks < 4; ++ks)
      #pragma unroll
      for (int m = 0; m < 8; ++m) {
        short8 b = *(const short8*)(&BW[(m * 16 + lr) * 136 + ks * 32 + kg * 8]);
        vacc[m] = mfma16(ea[ks], b, vacc[m]);
      }
    #pragma unroll
    for (int m = 0; m < 8; ++m) {
      float bb = bv[l * 128 + m * 16 + lr];
      #pragma unroll
      for (int r = 0; r < 4; ++r) {
        float x = vacc[m][r] + bb;
        x = x > 0.f ? x : 0.01f * x;
        Vbuf[(wave * 16 + kg * 4 + r) * 136 + m * 16 + lr] = f2bf(x);
      }
    }
    __syncthreads();
    stage_bt<16, 1152, 136>(BW, W1T + (size_t)i * 147456 + l * 128, tid);
    __syncthreads();
    const short* sp = SB + (size_t)(l * 8192 + rowbase + lr) * 128;
    #pragma unroll
    for (int ks = 0; ks < 4; ++ks) {
      short8 sv = *(const short8*)(sp + ks * 32 + kg * 8);
      short8 vv = *(const short8*)(&Vbuf[(wave * 16 + lr) * 136 + ks * 32 + kg * 8]);
      short8 a;
      #pragma unroll
      for (int jj = 0; jj < 8; ++jj) a[jj] = f2bf(bf2f(sv[jj]) - bf2f(vv[jj]));
      #pragma unroll
      for (int m = 0; m < 8; ++m) {
        short8 b = *(const short8*)(&BW[(m * 16 + lr) * 136 + ks * 32 + kg * 8]);
        hacc[m] = mfma16(a, b, hacc[m]);
      }
    }
  }
  __syncthreads();
  stage_bt<16, 1152, 136>(BW, W1T + (size_t)i * 147456 + 1024, tid);
  __syncthreads();
  #pragma unroll
  for (int ks = 0; ks < 4; ++ks)
    #pragma unroll
    for (int m = 0; m < 8; ++m) {
      short8 b = *(const short8*)(&BW[(m * 16 + lr) * 136 + ks * 32 + kg * 8]);
      hacc[m] = mfma16(ea[ks], b, hacc[m]);
    }
  float sacc[4] = {0.f, 0.f, 0.f, 0.f};
  #pragma unroll
  for (int m = 0; m < 8; ++m) {
    int col = m * 16 + lr;
    float b1v = b1[i * 128 + col];
    float w2v = W2[i * 128 + col];
    #pragma unroll
    for (int r = 0; r < 4; ++r) {
      float h = hacc[m][r] + b1v;
      h = h > 0.f ? h : 0.f;
      sacc[r] += h * w2v;
    }
  }
  #pragma unroll
  for (int r = 0; r < 4; ++r) {
    float s = sacc[r];
    s += __shfl_xor(s, 1);
    s += __shfl_xor(s, 2);
    s += __shfl_xor(s, 4);
    s += __shfl_xor(s, 8);
    if (lr == 0) out[i * 8192 + rowbase + kg * 4 + r] = s + b2[i];
  }
}

extern "C" void kernel_launch(void* const* d_in, const int* in_sizes, int n_in,
                              void* d_out, int out_size, void* d_ws, size_t ws_size,
                              hipStream_t stream) {
  const float* obs = (const float*)d_in[0];
  const float* act = (const float*)d_in[1];
  const float* Wg  = (const float*)d_in[2];
  const float* bg  = (const float*)d_in[3];
  // d_in[4..7] = Wq,bq,Wk,bk: dead (softmax over singleton axis == 1)
  const float* Wv  = (const float*)d_in[8];
  const float* bv  = (const float*)d_in[9];
  const float* W1  = (const float*)d_in[10];
  const float* b1  = (const float*)d_in[11];
  const float* W2  = (const float*)d_in[12];
  const float* b2  = (const float*)d_in[13];
  float* out = (float*)d_out;

  const size_t E_B = (size_t)8 * 8192 * 128;    // eB shorts
  const size_t A_B = (size_t)8 * 8192 * 1024;   // AB shorts
  const size_t NEED_BIG = (E_B + A_B + 163840 + 131072 + 1179648) * 2;  // bytes

  if (ws_size >= NEED_BIG) {
    short* eB  = (short*)d_ws;
    short* AB  = eB + E_B;
    short* WgT = AB + A_B;
    short* WvT = WgT + 163840;
    short* W1T = WvT + 131072;
    k0_tr<<<720, 256, 0, stream>>>(Wg, Wv, W1, WgT, WvT, W1T);
    k1_e<<<dim3(128, 8), 256, 0, stream>>>(obs, act, WgT, bg, eB);
    k2_A<<<dim3(128, 8), 256, 0, stream>>>(eB, WvT, bv, AB);
    k3_gemm<<<dim3(64, 8), 256, 0, stream>>>(eB, AB, W1T, b1, W2, b2, out);
  } else {
    short* eB  = (short*)d_ws;
    short* SB  = eB + E_B;
    short* WgT = SB + E_B;
    short* WvT = WgT + 163840;
    short* W1T = WvT + 131072;
    k0_tr<<<720, 256, 0, stream>>>(Wg, Wv, W1, WgT, WvT, W1T);
    k1_e<<<dim3(128, 8), 256, 0, stream>>>(obs, act, WgT, bg, eB);
    k2_S<<<dim3(128, 8), 256, 0, stream>>>(eB, WvT, bv, SB);
    k3_out<<<dim3(128, 8), 256, 0, stream>>>(eB, SB, WvT, W1T, bv, b1, W2, b2, out);
  }
}